// Round 1
// baseline (6327.011 us; speedup 1.0000x reference)
//
#include <hip/hip_runtime.h>

#define C0n 50000
#define C1n 150000
#define C2n 300000
#define E0n 300000
#define E1n 600000
#define NEn (E0n + E1n)

typedef float v4f __attribute__((ext_vector_type(4)));
typedef float v2f __attribute__((ext_vector_type(2)));

// ---------------- xp = relu(x @ Wp[t] + bp[t]), M=C2, K=64, N=64 ----------------
__global__ __launch_bounds__(256) void k_proj(const float* __restrict__ x,
    const float* __restrict__ Wp, const float* __restrict__ bp,
    float* __restrict__ xp)
{
    __shared__ float Ws[64 * 64];
    __shared__ float bs[64];
    const int tid = threadIdx.x;
    for (int i = tid; i < 64 * 64 / 4; i += 256)
        ((v4f*)Ws)[i] = ((const v4f*)Wp)[i];
    if (tid < 64) bs[tid] = bp[tid];
    __syncthreads();

    const int cg = tid & 15, rowg = tid >> 4;
    const int col = cg * 4;
    const long r0 = (long)blockIdx.x * 64 + rowg * 4;

    v4f acc[4];
    acc[0] = 0; acc[1] = 0; acc[2] = 0; acc[3] = 0;

    for (int k = 0; k < 64; k += 4) {
        v4f xr[4];
#pragma unroll
        for (int i = 0; i < 4; i++) {
            long r = r0 + i; if (r >= C2n) r = C2n - 1;
            xr[i] = *(const v4f*)&x[r * 64 + k];
        }
#pragma unroll
        for (int kk = 0; kk < 4; kk++) {
            v4f w = *(const v4f*)&Ws[(k + kk) * 64 + col];
#pragma unroll
            for (int i = 0; i < 4; i++)
                acc[i] += xr[i][kk] * w;
        }
    }
    v4f b = *(const v4f*)&bs[col];
#pragma unroll
    for (int i = 0; i < 4; i++) {
        long r = r0 + i;
        if (r >= C2n) break;
        v4f o = acc[i] + b;
#pragma unroll
        for (int j = 0; j < 4; j++) o[j] = fmaxf(o[j], 0.f);
        *(v4f*)&xp[r * 64 + col] = o;
    }
}

// ---------------- scatter layer1: agg[dst] += xp[src] (64 f), cnt[dst]++ ----------------
__global__ __launch_bounds__(256) void k_scat1(const int* __restrict__ src,
    const int* __restrict__ dst, const float* __restrict__ xp,
    float* __restrict__ agg, float* __restrict__ cnt, int nE)
{
    const int e = blockIdx.x * 4 + (threadIdx.x >> 6);
    if (e >= nE) return;
    const int lane = threadIdx.x & 63;
    const int s = src[e], d = dst[e];
    const float v = xp[(long)s * 64 + lane];
    atomicAdd(&agg[(long)d * 64 + lane], v);
    if (lane == 0) atomicAdd(&cnt[d], 1.0f);
}

// ------- o = (agg/cnt)@Wl + bl + x@Wr ; o /= max(||o||,eps) ; h += o  (rows < C1) -------
__global__ __launch_bounds__(256) void k_out1(const float* __restrict__ agg,
    const float* __restrict__ cnt, const float* __restrict__ x,
    const float* __restrict__ Wl, const float* __restrict__ Wr,
    const float* __restrict__ bl, float* __restrict__ h)
{
    __shared__ float Ws[64 * 128];
    __shared__ float bs[128];
    const int tid = threadIdx.x;
    for (int i = tid; i < 64 * 128 / 4; i += 256)
        ((v4f*)Ws)[i] = ((const v4f*)Wl)[i];
    if (tid < 128) bs[tid] = bl[tid];
    __syncthreads();

    const int cg = tid & 31, rowg = tid >> 5;
    const int col = cg * 4;
    const long r0 = (long)blockIdx.x * 32 + rowg * 4;

    v4f acc[4];
    acc[0] = 0; acc[1] = 0; acc[2] = 0; acc[3] = 0;

    // phase 1: agg @ Wl
    for (int k = 0; k < 64; k += 4) {
        v4f ar[4];
#pragma unroll
        for (int i = 0; i < 4; i++) {
            long r = r0 + i; if (r >= C1n) r = C1n - 1;
            ar[i] = *(const v4f*)&agg[r * 64 + k];
        }
#pragma unroll
        for (int kk = 0; kk < 4; kk++) {
            v4f w = *(const v4f*)&Ws[(k + kk) * 128 + col];
#pragma unroll
            for (int i = 0; i < 4; i++)
                acc[i] += ar[i][kk] * w;
        }
    }
    // seg-mean division (scalar per row commutes with the matmul)
#pragma unroll
    for (int i = 0; i < 4; i++) {
        long r = r0 + i; if (r >= C1n) r = C1n - 1;
        float c = cnt[r];
        acc[i] *= 1.f / fmaxf(c, 1.f);
    }
    __syncthreads();
    for (int i = tid; i < 64 * 128 / 4; i += 256)
        ((v4f*)Ws)[i] = ((const v4f*)Wr)[i];
    __syncthreads();

    // phase 2: + x @ Wr
    for (int k = 0; k < 64; k += 4) {
        v4f xr[4];
#pragma unroll
        for (int i = 0; i < 4; i++) {
            long r = r0 + i; if (r >= C1n) r = C1n - 1;
            xr[i] = *(const v4f*)&x[r * 64 + k];
        }
#pragma unroll
        for (int kk = 0; kk < 4; kk++) {
            v4f w = *(const v4f*)&Ws[(k + kk) * 128 + col];
#pragma unroll
            for (int i = 0; i < 4; i++)
                acc[i] += xr[i][kk] * w;
        }
    }

    v4f b = *(const v4f*)&bs[col];
#pragma unroll
    for (int i = 0; i < 4; i++) {
        acc[i] += b;
        // row L2 norm across the 32 threads owning this row (they are a contiguous
        // 32-lane half-wave: tid = rowg*32 + cg)
        float ss = acc[i][0]*acc[i][0] + acc[i][1]*acc[i][1]
                 + acc[i][2]*acc[i][2] + acc[i][3]*acc[i][3];
#pragma unroll
        for (int m = 16; m; m >>= 1) ss += __shfl_xor(ss, m);
        const float inv = 1.f / fmaxf(sqrtf(ss), 1e-12f);
        const long r = r0 + i;
        if (r < C1n) {
            v4f cur = *(v4f*)&h[r * 128 + col];
            cur += acc[i] * inv;
            *(v4f*)&h[r * 128 + col] = cur;
        }
    }
}

// ---------------- relu + layernorm (in place capable); v = src/3 first ----------------
__global__ __launch_bounds__(256) void k_ln(const float* __restrict__ src,
    float* __restrict__ dst, int nrows,
    const float* __restrict__ g, const float* __restrict__ b)
{
    const int rowg = threadIdx.x >> 6, lane = threadIdx.x & 63;
    const long row = (long)blockIdx.x * 4 + rowg;
    if (row >= nrows) return;
    v2f v = *(const v2f*)&src[row * 128 + lane * 2];
    v *= (1.0f / 3.0f);
    v[0] = fmaxf(v[0], 0.f); v[1] = fmaxf(v[1], 0.f);
    float s = v[0] + v[1];
#pragma unroll
    for (int m = 32; m; m >>= 1) s += __shfl_xor(s, m);
    const float mu = s * (1.0f / 128.0f);
    const float d0 = v[0] - mu, d1 = v[1] - mu;
    float vs = d0 * d0 + d1 * d1;
#pragma unroll
    for (int m = 32; m; m >>= 1) vs += __shfl_xor(vs, m);
    const float rs = rsqrtf(vs * (1.0f / 128.0f) + 1e-5f);
    v2f gv = *(const v2f*)&g[lane * 2];
    v2f bv = *(const v2f*)&b[lane * 2];
    v2f o;
    o[0] = d0 * rs * gv[0] + bv[0];
    o[1] = d1 * rs * gv[1] + bv[1];
    *(v2f*)&dst[row * 128 + lane * 2] = o;
}

// ---------------- scatter layer2: agg2[dst] += h1[src] (128 f), cnt2[dst]++ ----------------
__global__ __launch_bounds__(256) void k_scat2(const int* __restrict__ src,
    const int* __restrict__ dst, const float* __restrict__ h1,
    float* __restrict__ agg2, float* __restrict__ cnt2, int nE)
{
    const int e = blockIdx.x * 2 + (threadIdx.x >> 7);
    if (e >= nE) return;
    const int i = threadIdx.x & 127;
    const int s = src[e], d = dst[e];
    atomicAdd(&agg2[(long)d * 128 + i], h1[(long)s * 128 + i]);
    if (i == 0) atomicAdd(&cnt2[d], 1.0f);
}

// ------- h2 += (agg2/cnt2)@Wl2 + bl2 + h1@Wr2   (rows < C0) -------
__global__ __launch_bounds__(256) void k_out2(const float* __restrict__ agg2,
    const float* __restrict__ cnt2, const float* __restrict__ h1,
    const float* __restrict__ Wl2, const float* __restrict__ Wr2,
    const float* __restrict__ bl2, float* __restrict__ h2)
{
    __shared__ float Ws[128 * 128]; // 64 KiB
    __shared__ float bs[128];
    const int tid = threadIdx.x;
    for (int i = tid; i < 128 * 128 / 4; i += 256)
        ((v4f*)Ws)[i] = ((const v4f*)Wl2)[i];
    if (tid < 128) bs[tid] = bl2[tid];
    __syncthreads();

    const int cg = tid & 31, rowg = tid >> 5;
    const int col = cg * 4;
    const long r0 = (long)blockIdx.x * 32 + rowg * 4;

    v4f acc[4];
    acc[0] = 0; acc[1] = 0; acc[2] = 0; acc[3] = 0;

    for (int k = 0; k < 128; k += 4) {
        v4f ar[4];
#pragma unroll
        for (int i = 0; i < 4; i++) {
            long r = r0 + i; if (r >= C0n) r = C0n - 1;
            ar[i] = *(const v4f*)&agg2[r * 128 + k];
        }
#pragma unroll
        for (int kk = 0; kk < 4; kk++) {
            v4f w = *(const v4f*)&Ws[(k + kk) * 128 + col];
#pragma unroll
            for (int i = 0; i < 4; i++)
                acc[i] += ar[i][kk] * w;
        }
    }
#pragma unroll
    for (int i = 0; i < 4; i++) {
        long r = r0 + i; if (r >= C0n) r = C0n - 1;
        float c = cnt2[r];
        acc[i] *= 1.f / fmaxf(c, 1.f);
    }
    __syncthreads();
    for (int i = tid; i < 128 * 128 / 4; i += 256)
        ((v4f*)Ws)[i] = ((const v4f*)Wr2)[i];
    __syncthreads();

    for (int k = 0; k < 128; k += 4) {
        v4f xr[4];
#pragma unroll
        for (int i = 0; i < 4; i++) {
            long r = r0 + i; if (r >= C0n) r = C0n - 1;
            xr[i] = *(const v4f*)&h1[r * 128 + k];
        }
#pragma unroll
        for (int kk = 0; kk < 4; kk++) {
            v4f w = *(const v4f*)&Ws[(k + kk) * 128 + col];
#pragma unroll
            for (int i = 0; i < 4; i++)
                acc[i] += xr[i][kk] * w;
        }
    }

    v4f b = *(const v4f*)&bs[col];
#pragma unroll
    for (int i = 0; i < 4; i++) {
        const long r = r0 + i;
        if (r < C0n) {
            v4f cur = *(v4f*)&h2[r * 128 + col];
            cur += acc[i] + b;
            *(v4f*)&h2[r * 128 + col] = cur;
        }
    }
}

extern "C" void kernel_launch(void* const* d_in, const int* in_sizes, int n_in,
                              void* d_out, int out_size, void* d_ws, size_t ws_size,
                              hipStream_t stream)
{
    const float* x   = (const float*)d_in[0];
    const int*   ei[3] = { (const int*)d_in[1], (const int*)d_in[2], (const int*)d_in[3] };
    const float* Wp  = (const float*)d_in[6];
    const float* bp  = (const float*)d_in[7];
    const float* Wl  = (const float*)d_in[8];
    const float* bl  = (const float*)d_in[9];
    const float* Wr  = (const float*)d_in[10];
    const float* Wl2 = (const float*)d_in[11];
    const float* bl2 = (const float*)d_in[12];
    const float* Wr2 = (const float*)d_in[13];
    const float* g0  = (const float*)d_in[14];
    const float* b0  = (const float*)d_in[15];
    const float* g1  = (const float*)d_in[16];
    const float* b1  = (const float*)d_in[17];

    // workspace layout (floats):
    float* agg  = (float*)d_ws;                 // C1*64
    float* cnt  = agg + (size_t)C1n * 64;       // C1
    float* h    = cnt + C1n;                    // C1*128
    float* xp   = h + (size_t)C1n * 128;        // C2*64  (layer-1 only)
    float* agg2 = xp;                           // C0*128 (overlays xp)
    float* cnt2 = agg2 + (size_t)C0n * 128;     // C0
    float* h2   = cnt2 + C0n;                   // C0*128

    hipMemsetAsync(h, 0, (size_t)C1n * 128 * 4, stream);

    for (int t = 0; t < 3; t++) {
        hipMemsetAsync(agg, 0, ((size_t)C1n * 64 + C1n) * 4, stream);
        k_proj<<<(C2n + 63) / 64, 256, 0, stream>>>(x, Wp + (size_t)t * 64 * 64,
                                                    bp + (size_t)t * 64, xp);
        k_scat1<<<(NEn + 3) / 4, 256, 0, stream>>>(ei[t], ei[t] + NEn, xp, agg, cnt, NEn);
        k_out1<<<(C1n + 31) / 32, 256, 0, stream>>>(agg, cnt, x,
                                                    Wl + (size_t)t * 64 * 128,
                                                    Wr + (size_t)t * 64 * 128,
                                                    bl + (size_t)t * 128, h);
    }
    k_ln<<<(C1n + 3) / 4, 256, 0, stream>>>(h, h, C1n, g0, b0);

    hipMemsetAsync(h2, 0, (size_t)C0n * 128 * 4, stream);
    for (int t = 0; t < 3; t++) {
        hipMemsetAsync(agg2, 0, ((size_t)C0n * 128 + C0n) * 4, stream);
        k_scat2<<<(E0n + 1) / 2, 256, 0, stream>>>(ei[t], ei[t] + NEn, h, agg2, cnt2, E0n);
        k_out2<<<(C0n + 31) / 32, 256, 0, stream>>>(agg2, cnt2, h,
                                                    Wl2 + (size_t)t * 128 * 128,
                                                    Wr2 + (size_t)t * 128 * 128,
                                                    bl2 + (size_t)t * 128, h2);
    }
    k_ln<<<(C0n + 3) / 4, 256, 0, stream>>>(h2, (float*)d_out, C0n, g1, b1);
}

// Round 2
// 2030.390 us; speedup vs baseline: 3.1162x; 3.1162x over previous
//
#include <hip/hip_runtime.h>

#define C0n 50000
#define C1n 150000
#define C2n 300000
#define E0n 300000
#define E1n 600000
#define NEn (E0n + E1n)

typedef float v4f __attribute__((ext_vector_type(4)));
typedef float v2f __attribute__((ext_vector_type(2)));

// ---------------- xp = relu(x @ Wp[t] + bp[t]), M=C2, K=64, N=64 ----------------
__global__ __launch_bounds__(256) void k_proj(const float* __restrict__ x,
    const float* __restrict__ Wp, const float* __restrict__ bp,
    float* __restrict__ xp)
{
    __shared__ float Ws[64 * 64];
    __shared__ float bs[64];
    const int tid = threadIdx.x;
    for (int i = tid; i < 64 * 64 / 4; i += 256)
        ((v4f*)Ws)[i] = ((const v4f*)Wp)[i];
    if (tid < 64) bs[tid] = bp[tid];
    __syncthreads();

    const int cg = tid & 15, rowg = tid >> 4;
    const int col = cg * 4;
    const int r0 = blockIdx.x * 64 + rowg * 4;

    // precompute clamped row offsets ONCE (keeps the K-loop body small)
    int ro[4];
#pragma unroll
    for (int i = 0; i < 4; i++) {
        int r = r0 + i; if (r >= C2n) r = C2n - 1;
        ro[i] = r * 64;
    }

    v4f acc[4];
    acc[0] = 0; acc[1] = 0; acc[2] = 0; acc[3] = 0;

#pragma unroll 4
    for (int k = 0; k < 64; k += 4) {
        v4f xr[4];
#pragma unroll
        for (int i = 0; i < 4; i++)
            xr[i] = *(const v4f*)&x[ro[i] + k];
#pragma unroll
        for (int kk = 0; kk < 4; kk++) {
            v4f w = *(const v4f*)&Ws[(k + kk) * 64 + col];
#pragma unroll
            for (int i = 0; i < 4; i++)
                acc[i] += xr[i][kk] * w;
        }
    }
    v4f b = *(const v4f*)&bs[col];
#pragma unroll
    for (int i = 0; i < 4; i++) {
        int r = r0 + i;
        if (r >= C2n) break;
        v4f o = acc[i] + b;
#pragma unroll
        for (int j = 0; j < 4; j++) o[j] = fmaxf(o[j], 0.f);
        *(v4f*)&xp[r * 64 + col] = o;
    }
}

// ---------------- scatter layer1: agg[dst] += xp[src] (64 f), cnt[dst]++ ----------------
__global__ __launch_bounds__(256) void k_scat1(const int* __restrict__ src,
    const int* __restrict__ dst, const float* __restrict__ xp,
    float* __restrict__ agg, float* __restrict__ cnt, int nE)
{
    const int e = blockIdx.x * 4 + (threadIdx.x >> 6);
    if (e >= nE) return;
    const int lane = threadIdx.x & 63;
    const int s = src[e], d = dst[e];
    const float v = xp[(long)s * 64 + lane];
    atomicAdd(&agg[(long)d * 64 + lane], v);
    if (lane == 0) atomicAdd(&cnt[d], 1.0f);
}

// ------- o = (agg/cnt)@Wl + bl + x@Wr ; o /= max(||o||,eps) ; h += o  (rows < C1) -------
__global__ __launch_bounds__(256) void k_out1(const float* __restrict__ agg,
    const float* __restrict__ cnt, const float* __restrict__ x,
    const float* __restrict__ Wl, const float* __restrict__ Wr,
    const float* __restrict__ bl, float* __restrict__ h)
{
    __shared__ float Ws[64 * 128];
    __shared__ float bs[128];
    const int tid = threadIdx.x;
    for (int i = tid; i < 64 * 128 / 4; i += 256)
        ((v4f*)Ws)[i] = ((const v4f*)Wl)[i];
    if (tid < 128) bs[tid] = bl[tid];
    __syncthreads();

    const int cg = tid & 31, rowg = tid >> 5;
    const int col = cg * 4;
    const int r0 = blockIdx.x * 32 + rowg * 4;

    int ro[4];
#pragma unroll
    for (int i = 0; i < 4; i++) {
        int r = r0 + i; if (r >= C1n) r = C1n - 1;
        ro[i] = r * 64;
    }

    v4f acc[4];
    acc[0] = 0; acc[1] = 0; acc[2] = 0; acc[3] = 0;

    // phase 1: agg @ Wl
#pragma unroll 4
    for (int k = 0; k < 64; k += 4) {
        v4f ar[4];
#pragma unroll
        for (int i = 0; i < 4; i++)
            ar[i] = *(const v4f*)&agg[ro[i] + k];
#pragma unroll
        for (int kk = 0; kk < 4; kk++) {
            v4f w = *(const v4f*)&Ws[(k + kk) * 128 + col];
#pragma unroll
            for (int i = 0; i < 4; i++)
                acc[i] += ar[i][kk] * w;
        }
    }
    // seg-mean division (scalar per row commutes with the matmul)
#pragma unroll
    for (int i = 0; i < 4; i++) {
        float c = cnt[ro[i] >> 6];
        acc[i] *= 1.f / fmaxf(c, 1.f);
    }
    __syncthreads();
    for (int i = tid; i < 64 * 128 / 4; i += 256)
        ((v4f*)Ws)[i] = ((const v4f*)Wr)[i];
    __syncthreads();

    // phase 2: + x @ Wr
#pragma unroll 4
    for (int k = 0; k < 64; k += 4) {
        v4f xr[4];
#pragma unroll
        for (int i = 0; i < 4; i++)
            xr[i] = *(const v4f*)&x[ro[i] + k];
#pragma unroll
        for (int kk = 0; kk < 4; kk++) {
            v4f w = *(const v4f*)&Ws[(k + kk) * 128 + col];
#pragma unroll
            for (int i = 0; i < 4; i++)
                acc[i] += xr[i][kk] * w;
        }
    }

    v4f b = *(const v4f*)&bs[col];
#pragma unroll
    for (int i = 0; i < 4; i++) {
        acc[i] += b;
        // row L2 norm across the 32 threads owning this row (contiguous half-wave)
        float ss = acc[i][0]*acc[i][0] + acc[i][1]*acc[i][1]
                 + acc[i][2]*acc[i][2] + acc[i][3]*acc[i][3];
#pragma unroll
        for (int m = 16; m; m >>= 1) ss += __shfl_xor(ss, m);
        const float inv = 1.f / fmaxf(sqrtf(ss), 1e-12f);
        const int r = r0 + i;
        if (r < C1n) {
            v4f cur = *(v4f*)&h[(long)r * 128 + col];
            cur += acc[i] * inv;
            *(v4f*)&h[(long)r * 128 + col] = cur;
        }
    }
}

// ---------------- relu + layernorm; v = src/3 first ----------------
__global__ __launch_bounds__(256) void k_ln(const float* __restrict__ src,
    float* __restrict__ dst, int nrows,
    const float* __restrict__ g, const float* __restrict__ b)
{
    const int rowg = threadIdx.x >> 6, lane = threadIdx.x & 63;
    const long row = (long)blockIdx.x * 4 + rowg;
    if (row >= nrows) return;
    v2f v = *(const v2f*)&src[row * 128 + lane * 2];
    v *= (1.0f / 3.0f);
    v[0] = fmaxf(v[0], 0.f); v[1] = fmaxf(v[1], 0.f);
    float s = v[0] + v[1];
#pragma unroll
    for (int m = 32; m; m >>= 1) s += __shfl_xor(s, m);
    const float mu = s * (1.0f / 128.0f);
    const float d0 = v[0] - mu, d1 = v[1] - mu;
    float vs = d0 * d0 + d1 * d1;
#pragma unroll
    for (int m = 32; m; m >>= 1) vs += __shfl_xor(vs, m);
    const float rs = rsqrtf(vs * (1.0f / 128.0f) + 1e-5f);
    v2f gv = *(const v2f*)&g[lane * 2];
    v2f bv = *(const v2f*)&b[lane * 2];
    v2f o;
    o[0] = d0 * rs * gv[0] + bv[0];
    o[1] = d1 * rs * gv[1] + bv[1];
    *(v2f*)&dst[row * 128 + lane * 2] = o;
}

// ---------------- scatter layer2: agg2[dst] += h1[src] (128 f), cnt2[dst]++ ----------------
__global__ __launch_bounds__(256) void k_scat2(const int* __restrict__ src,
    const int* __restrict__ dst, const float* __restrict__ h1,
    float* __restrict__ agg2, float* __restrict__ cnt2, int nE)
{
    const int e = blockIdx.x * 2 + (threadIdx.x >> 7);
    if (e >= nE) return;
    const int i = threadIdx.x & 127;
    const int s = src[e], d = dst[e];
    atomicAdd(&agg2[(long)d * 128 + i], h1[(long)s * 128 + i]);
    if (i == 0) atomicAdd(&cnt2[d], 1.0f);
}

// ------- h2 += (agg2/cnt2)@Wl2 + bl2 + h1@Wr2   (rows < C0) -------
__global__ __launch_bounds__(256) void k_out2(const float* __restrict__ agg2,
    const float* __restrict__ cnt2, const float* __restrict__ h1,
    const float* __restrict__ Wl2, const float* __restrict__ Wr2,
    const float* __restrict__ bl2, float* __restrict__ h2)
{
    __shared__ float Ws[128 * 128]; // 64 KiB
    __shared__ float bs[128];
    const int tid = threadIdx.x;
    for (int i = tid; i < 128 * 128 / 4; i += 256)
        ((v4f*)Ws)[i] = ((const v4f*)Wl2)[i];
    if (tid < 128) bs[tid] = bl2[tid];
    __syncthreads();

    const int cg = tid & 31, rowg = tid >> 5;
    const int col = cg * 4;
    const int r0 = blockIdx.x * 32 + rowg * 4;

    int ro[4];
#pragma unroll
    for (int i = 0; i < 4; i++) {
        int r = r0 + i; if (r >= C0n) r = C0n - 1;
        ro[i] = r * 128;
    }

    v4f acc[4];
    acc[0] = 0; acc[1] = 0; acc[2] = 0; acc[3] = 0;

#pragma unroll 4
    for (int k = 0; k < 128; k += 4) {
        v4f ar[4];
#pragma unroll
        for (int i = 0; i < 4; i++)
            ar[i] = *(const v4f*)&agg2[ro[i] + k];
#pragma unroll
        for (int kk = 0; kk < 4; kk++) {
            v4f w = *(const v4f*)&Ws[(k + kk) * 128 + col];
#pragma unroll
            for (int i = 0; i < 4; i++)
                acc[i] += ar[i][kk] * w;
        }
    }
#pragma unroll
    for (int i = 0; i < 4; i++) {
        float c = cnt2[ro[i] >> 7];
        acc[i] *= 1.f / fmaxf(c, 1.f);
    }
    __syncthreads();
    for (int i = tid; i < 128 * 128 / 4; i += 256)
        ((v4f*)Ws)[i] = ((const v4f*)Wr2)[i];
    __syncthreads();

#pragma unroll 4
    for (int k = 0; k < 128; k += 4) {
        v4f xr[4];
#pragma unroll
        for (int i = 0; i < 4; i++)
            xr[i] = *(const v4f*)&h1[ro[i] + k];
#pragma unroll
        for (int kk = 0; kk < 4; kk++) {
            v4f w = *(const v4f*)&Ws[(k + kk) * 128 + col];
#pragma unroll
            for (int i = 0; i < 4; i++)
                acc[i] += xr[i][kk] * w;
        }
    }

    v4f b = *(const v4f*)&bs[col];
#pragma unroll
    for (int i = 0; i < 4; i++) {
        const int r = r0 + i;
        if (r < C0n) {
            v4f cur = *(v4f*)&h2[(long)r * 128 + col];
            cur += acc[i] + b;
            *(v4f*)&h2[(long)r * 128 + col] = cur;
        }
    }
}

extern "C" void kernel_launch(void* const* d_in, const int* in_sizes, int n_in,
                              void* d_out, int out_size, void* d_ws, size_t ws_size,
                              hipStream_t stream)
{
    const float* x   = (const float*)d_in[0];
    const int*   ei[3] = { (const int*)d_in[1], (const int*)d_in[2], (const int*)d_in[3] };
    const float* Wp  = (const float*)d_in[6];
    const float* bp  = (const float*)d_in[7];
    const float* Wl  = (const float*)d_in[8];
    const float* bl  = (const float*)d_in[9];
    const float* Wr  = (const float*)d_in[10];
    const float* Wl2 = (const float*)d_in[11];
    const float* bl2 = (const float*)d_in[12];
    const float* Wr2 = (const float*)d_in[13];
    const float* g0  = (const float*)d_in[14];
    const float* b0  = (const float*)d_in[15];
    const float* g1  = (const float*)d_in[16];
    const float* b1  = (const float*)d_in[17];

    // workspace layout (floats):
    float* agg  = (float*)d_ws;                 // C1*64
    float* cnt  = agg + (size_t)C1n * 64;       // C1
    float* h    = cnt + C1n;                    // C1*128
    float* xp   = h + (size_t)C1n * 128;        // C2*64  (layer-1 only)
    float* agg2 = xp;                           // C0*128 (overlays xp)
    float* cnt2 = agg2 + (size_t)C0n * 128;     // C0
    float* h2   = cnt2 + C0n;                   // C0*128

    hipMemsetAsync(h, 0, (size_t)C1n * 128 * 4, stream);

    for (int t = 0; t < 3; t++) {
        hipMemsetAsync(agg, 0, ((size_t)C1n * 64 + C1n) * 4, stream);
        k_proj<<<(C2n + 63) / 64, 256, 0, stream>>>(x, Wp + (size_t)t * 64 * 64,
                                                    bp + (size_t)t * 64, xp);
        k_scat1<<<(NEn + 3) / 4, 256, 0, stream>>>(ei[t], ei[t] + NEn, xp, agg, cnt, NEn);
        k_out1<<<(C1n + 31) / 32, 256, 0, stream>>>(agg, cnt, x,
                                                    Wl + (size_t)t * 64 * 128,
                                                    Wr + (size_t)t * 64 * 128,
                                                    bl + (size_t)t * 128, h);
    }
    k_ln<<<(C1n + 3) / 4, 256, 0, stream>>>(h, h, C1n, g0, b0);

    hipMemsetAsync(h2, 0, (size_t)C0n * 128 * 4, stream);
    for (int t = 0; t < 3; t++) {
        hipMemsetAsync(agg2, 0, ((size_t)C0n * 128 + C0n) * 4, stream);
        k_scat2<<<(E0n + 1) / 2, 256, 0, stream>>>(ei[t], ei[t] + NEn, h, agg2, cnt2, E0n);
        k_out2<<<(C0n + 31) / 32, 256, 0, stream>>>(agg2, cnt2, h,
                                                    Wl2 + (size_t)t * 128 * 128,
                                                    Wr2 + (size_t)t * 128 * 128,
                                                    bl2 + (size_t)t * 128, h2);
    }
    k_ln<<<(C0n + 3) / 4, 256, 0, stream>>>(h2, (float*)d_out, C0n, g1, b1);
}

// Round 3
// 1508.309 us; speedup vs baseline: 4.1948x; 1.3461x over previous
//
#include <hip/hip_runtime.h>

#define C0n 50000
#define C1n 150000
#define C2n 300000
#define E0n 300000
#define E1n 600000
#define NEn (E0n + E1n)

typedef float v4f __attribute__((ext_vector_type(4)));
typedef float v2f __attribute__((ext_vector_type(2)));
typedef unsigned short v4h __attribute__((ext_vector_type(4)));

__device__ __forceinline__ unsigned short f2bf(float f){
    unsigned u = __builtin_bit_cast(unsigned, f);
    u += 0x7FFFu + ((u >> 16) & 1u);          // RNE
    return (unsigned short)(u >> 16);
}
__device__ __forceinline__ float bf2f(unsigned short h){
    unsigned u = ((unsigned)h) << 16;
    return __builtin_bit_cast(float, u);
}

// ---------------- xp = relu(x @ Wp[t] + bp[t]) -> bf16, M=C2, K=64, N=64 ----------------
__global__ __launch_bounds__(256) void k_proj(const float* __restrict__ x,
    const float* __restrict__ Wp, const float* __restrict__ bp,
    unsigned short* __restrict__ xp)
{
    __shared__ float Ws[64 * 64];
    __shared__ float bs[64];
    const int tid = threadIdx.x;
    for (int i = tid; i < 64 * 64 / 4; i += 256)
        ((v4f*)Ws)[i] = ((const v4f*)Wp)[i];
    if (tid < 64) bs[tid] = bp[tid];
    __syncthreads();

    const int cg = tid & 15, rowg = tid >> 4;
    const int col = cg * 4;
    const int r0 = blockIdx.x * 64 + rowg * 4;

    int ro[4];
#pragma unroll
    for (int i = 0; i < 4; i++) {
        int r = r0 + i; if (r >= C2n) r = C2n - 1;
        ro[i] = r * 64;
    }

    v4f acc[4];
    acc[0] = 0; acc[1] = 0; acc[2] = 0; acc[3] = 0;

#pragma unroll 4
    for (int k = 0; k < 64; k += 4) {
        v4f xr[4];
#pragma unroll
        for (int i = 0; i < 4; i++)
            xr[i] = *(const v4f*)&x[ro[i] + k];
#pragma unroll
        for (int kk = 0; kk < 4; kk++) {
            v4f w = *(const v4f*)&Ws[(k + kk) * 64 + col];
#pragma unroll
            for (int i = 0; i < 4; i++)
                acc[i] += xr[i][kk] * w;
        }
    }
    v4f b = *(const v4f*)&bs[col];
#pragma unroll
    for (int i = 0; i < 4; i++) {
        int r = r0 + i;
        if (r >= C2n) break;
        v4f o = acc[i] + b;
        v4h oh;
#pragma unroll
        for (int j = 0; j < 4; j++) oh[j] = f2bf(fmaxf(o[j], 0.f));
        *(v4h*)&xp[r * 64 + col] = oh;
    }
}

// ---------------- CSR build: histogram ----------------
__global__ __launch_bounds__(256) void k_hist(const int* __restrict__ d0,
    const int* __restrict__ d1, const int* __restrict__ d2,
    int* __restrict__ deg, int nE, int nV)
{
    const int e = blockIdx.x * 256 + threadIdx.x;
    if (e >= nE) return;
    const int y = blockIdx.y;
    const int* d = (y == 0) ? d0 : (y == 1) ? d1 : d2;
    atomicAdd(&deg[y * nV + d[e]], 1);
}

// ---------------- CSR build: 3-kernel exclusive scan (in place) ----------------
__global__ __launch_bounds__(256) void k_scan_a(int* __restrict__ a, int n,
    int* __restrict__ bsum, int nblk)
{
    __shared__ int sd[256];
    const int t = threadIdx.x, y = blockIdx.y;
    int* arr = a + (size_t)y * n;
    const int base = blockIdx.x * 2048 + t * 8;
    int v[8];
#pragma unroll
    for (int j = 0; j < 8; j++) v[j] = (base + j < n) ? arr[base + j] : 0;
    int tot = 0;
#pragma unroll
    for (int j = 0; j < 8; j++) { int tmp = v[j]; v[j] = tot; tot += tmp; }
    sd[t] = tot; __syncthreads();
    for (int off = 1; off < 256; off <<= 1) {
        int xv = (t >= off) ? sd[t - off] : 0;
        __syncthreads();
        sd[t] += xv;
        __syncthreads();
    }
    const int excl = sd[t] - tot;
#pragma unroll
    for (int j = 0; j < 8; j++)
        if (base + j < n) arr[base + j] = excl + v[j];
    if (t == 255) bsum[y * nblk + blockIdx.x] = sd[255];
}

__global__ __launch_bounds__(256) void k_scan_b(int* __restrict__ bsum, int nblk)
{
    __shared__ int sd[256];
    const int t = threadIdx.x, y = blockIdx.y;
    int val = (t < nblk) ? bsum[y * nblk + t] : 0;
    sd[t] = val; __syncthreads();
    for (int off = 1; off < 256; off <<= 1) {
        int xv = (t >= off) ? sd[t - off] : 0;
        __syncthreads();
        sd[t] += xv;
        __syncthreads();
    }
    if (t < nblk) bsum[y * nblk + t] = sd[t] - val;
}

__global__ __launch_bounds__(256) void k_scan_c(int* __restrict__ a, int n,
    const int* __restrict__ bsum, int nblk)
{
    const int t = threadIdx.x, y = blockIdx.y;
    int* arr = a + (size_t)y * n;
    const int base = blockIdx.x * 2048 + t * 8;
    const int add = bsum[y * nblk + blockIdx.x];
#pragma unroll
    for (int j = 0; j < 8; j++)
        if (base + j < n) arr[base + j] += add;
}

// ---------------- CSR build: fill (bucket permute) ----------------
__global__ __launch_bounds__(256) void k_fill(const int* __restrict__ s0,
    const int* __restrict__ s1, const int* __restrict__ s2,
    const int* __restrict__ d0, const int* __restrict__ d1, const int* __restrict__ d2,
    const int* __restrict__ rp, int* __restrict__ fill, int* __restrict__ el,
    int nE, int nV)
{
    const int e = blockIdx.x * 256 + threadIdx.x;
    if (e >= nE) return;
    const int y = blockIdx.y;
    const int* s = (y == 0) ? s0 : (y == 1) ? s1 : s2;
    const int* d = (y == 0) ? d0 : (y == 1) ? d1 : d2;
    const int dd = d[e];
    const int pos = rp[(size_t)y * nV + dd] + atomicAdd(&fill[(size_t)y * nV + dd], 1);
    el[(size_t)y * nE + pos] = s[e];
}

// ---------------- gather layer1: agg[r] = mean of xp[src] (64 bf16 -> f32) ----------------
__global__ __launch_bounds__(256) void k_gath1(const int* __restrict__ rp,
    const int* __restrict__ el, const unsigned short* __restrict__ xp,
    float* __restrict__ agg)
{
    const int gid = blockIdx.x * 4 + (threadIdx.x >> 6);
    if (gid >= C1n) return;
    const int lane = threadIdx.x & 63;
    const int b = rp[gid];
    const int e = (gid == C1n - 1) ? NEn : rp[gid + 1];
    float s = 0.f;
    for (int i = b; i < e; i++) {
        const int sr = el[i];
        s += bf2f(xp[sr * 64 + lane]);
    }
    const float inv = 1.f / (float)max(e - b, 1);
    agg[(size_t)gid * 64 + lane] = s * inv;
}

// ------- o = agg@Wl + bl + x@Wr ; o /= max(||o||,eps) ; h (=| +=) o  (rows < C1) -------
__global__ __launch_bounds__(256) void k_out1(const float* __restrict__ agg,
    const float* __restrict__ x,
    const float* __restrict__ Wl, const float* __restrict__ Wr,
    const float* __restrict__ bl, float* __restrict__ h, int first)
{
    __shared__ float Ws[64 * 128];
    __shared__ float bs[128];
    const int tid = threadIdx.x;
    for (int i = tid; i < 64 * 128 / 4; i += 256)
        ((v4f*)Ws)[i] = ((const v4f*)Wl)[i];
    if (tid < 128) bs[tid] = bl[tid];
    __syncthreads();

    const int cg = tid & 31, rowg = tid >> 5;
    const int col = cg * 4;
    const int r0 = blockIdx.x * 32 + rowg * 4;

    int ro[4];
#pragma unroll
    for (int i = 0; i < 4; i++) {
        int r = r0 + i; if (r >= C1n) r = C1n - 1;
        ro[i] = r * 64;
    }

    v4f acc[4];
    acc[0] = 0; acc[1] = 0; acc[2] = 0; acc[3] = 0;

    // phase 1: agg @ Wl
#pragma unroll 4
    for (int k = 0; k < 64; k += 4) {
        v4f ar[4];
#pragma unroll
        for (int i = 0; i < 4; i++)
            ar[i] = *(const v4f*)&agg[ro[i] + k];
#pragma unroll
        for (int kk = 0; kk < 4; kk++) {
            v4f w = *(const v4f*)&Ws[(k + kk) * 128 + col];
#pragma unroll
            for (int i = 0; i < 4; i++)
                acc[i] += ar[i][kk] * w;
        }
    }
    __syncthreads();
    for (int i = tid; i < 64 * 128 / 4; i += 256)
        ((v4f*)Ws)[i] = ((const v4f*)Wr)[i];
    __syncthreads();

    // phase 2: + x @ Wr
#pragma unroll 4
    for (int k = 0; k < 64; k += 4) {
        v4f xr[4];
#pragma unroll
        for (int i = 0; i < 4; i++)
            xr[i] = *(const v4f*)&x[ro[i] + k];
#pragma unroll
        for (int kk = 0; kk < 4; kk++) {
            v4f w = *(const v4f*)&Ws[(k + kk) * 128 + col];
#pragma unroll
            for (int i = 0; i < 4; i++)
                acc[i] += xr[i][kk] * w;
        }
    }

    v4f b = *(const v4f*)&bs[col];
#pragma unroll
    for (int i = 0; i < 4; i++) {
        acc[i] += b;
        float ss = acc[i][0]*acc[i][0] + acc[i][1]*acc[i][1]
                 + acc[i][2]*acc[i][2] + acc[i][3]*acc[i][3];
#pragma unroll
        for (int m = 16; m; m >>= 1) ss += __shfl_xor(ss, m);
        const float inv = 1.f / fmaxf(sqrtf(ss), 1e-12f);
        const int r = r0 + i;
        if (r < C1n) {
            v4f val = acc[i] * inv;
            if (!first) val += *(v4f*)&h[(size_t)r * 128 + col];
            *(v4f*)&h[(size_t)r * 128 + col] = val;
        }
    }
}

// ---------------- relu + layernorm; v = src/3 first ----------------
__global__ __launch_bounds__(256) void k_ln(const float* __restrict__ src,
    float* __restrict__ dst, int nrows,
    const float* __restrict__ g, const float* __restrict__ b)
{
    const int rowg = threadIdx.x >> 6, lane = threadIdx.x & 63;
    const long row = (long)blockIdx.x * 4 + rowg;
    if (row >= nrows) return;
    v2f v = *(const v2f*)&src[row * 128 + lane * 2];
    v *= (1.0f / 3.0f);
    v[0] = fmaxf(v[0], 0.f); v[1] = fmaxf(v[1], 0.f);
    float s = v[0] + v[1];
#pragma unroll
    for (int m = 32; m; m >>= 1) s += __shfl_xor(s, m);
    const float mu = s * (1.0f / 128.0f);
    const float d0 = v[0] - mu, d1 = v[1] - mu;
    float vs = d0 * d0 + d1 * d1;
#pragma unroll
    for (int m = 32; m; m >>= 1) vs += __shfl_xor(vs, m);
    const float rs = rsqrtf(vs * (1.0f / 128.0f) + 1e-5f);
    v2f gv = *(const v2f*)&g[lane * 2];
    v2f bv = *(const v2f*)&b[lane * 2];
    v2f o;
    o[0] = d0 * rs * gv[0] + bv[0];
    o[1] = d1 * rs * gv[1] + bv[1];
    *(v2f*)&dst[row * 128 + lane * 2] = o;
}

// ---------------- gather layer2: agg2[r] = mean of h1[src] (128 f32) ----------------
__global__ __launch_bounds__(256) void k_gath2(const int* __restrict__ rp,
    const int* __restrict__ el, const float* __restrict__ h1,
    float* __restrict__ agg2)
{
    const int gid = blockIdx.x * 4 + (threadIdx.x >> 6);
    if (gid >= C0n) return;
    const int lane = threadIdx.x & 63;
    const int b = rp[gid];
    const int e = (gid == C0n - 1) ? E0n : rp[gid + 1];
    v2f s; s[0] = 0.f; s[1] = 0.f;
    for (int i = b; i < e; i++) {
        const int sr = el[i];
        s += *(const v2f*)&h1[(size_t)sr * 128 + lane * 2];
    }
    const float inv = 1.f / (float)max(e - b, 1);
    *(v2f*)&agg2[(size_t)gid * 128 + lane * 2] = s * inv;
}

// ------- h2 (=| +=) agg2@Wl2 + bl2 + h1@Wr2   (rows < C0) -------
__global__ __launch_bounds__(256) void k_out2(const float* __restrict__ agg2,
    const float* __restrict__ h1,
    const float* __restrict__ Wl2, const float* __restrict__ Wr2,
    const float* __restrict__ bl2, float* __restrict__ h2, int first)
{
    __shared__ float Ws[128 * 128]; // 64 KiB
    __shared__ float bs[128];
    const int tid = threadIdx.x;
    for (int i = tid; i < 128 * 128 / 4; i += 256)
        ((v4f*)Ws)[i] = ((const v4f*)Wl2)[i];
    if (tid < 128) bs[tid] = bl2[tid];
    __syncthreads();

    const int cg = tid & 31, rowg = tid >> 5;
    const int col = cg * 4;
    const int r0 = blockIdx.x * 32 + rowg * 4;

    int ro[4];
#pragma unroll
    for (int i = 0; i < 4; i++) {
        int r = r0 + i; if (r >= C0n) r = C0n - 1;
        ro[i] = r * 128;
    }

    v4f acc[4];
    acc[0] = 0; acc[1] = 0; acc[2] = 0; acc[3] = 0;

#pragma unroll 4
    for (int k = 0; k < 128; k += 4) {
        v4f ar[4];
#pragma unroll
        for (int i = 0; i < 4; i++)
            ar[i] = *(const v4f*)&agg2[ro[i] + k];
#pragma unroll
        for (int kk = 0; kk < 4; kk++) {
            v4f w = *(const v4f*)&Ws[(k + kk) * 128 + col];
#pragma unroll
            for (int i = 0; i < 4; i++)
                acc[i] += ar[i][kk] * w;
        }
    }
    __syncthreads();
    for (int i = tid; i < 128 * 128 / 4; i += 256)
        ((v4f*)Ws)[i] = ((const v4f*)Wr2)[i];
    __syncthreads();

#pragma unroll 4
    for (int k = 0; k < 128; k += 4) {
        v4f xr[4];
#pragma unroll
        for (int i = 0; i < 4; i++)
            xr[i] = *(const v4f*)&h1[ro[i] + k];
#pragma unroll
        for (int kk = 0; kk < 4; kk++) {
            v4f w = *(const v4f*)&Ws[(k + kk) * 128 + col];
#pragma unroll
            for (int i = 0; i < 4; i++)
                acc[i] += xr[i][kk] * w;
        }
    }

    v4f b = *(const v4f*)&bs[col];
#pragma unroll
    for (int i = 0; i < 4; i++) {
        const int r = r0 + i;
        if (r < C0n) {
            v4f val = acc[i] + b;
            if (!first) val += *(v4f*)&h2[(size_t)r * 128 + col];
            *(v4f*)&h2[(size_t)r * 128 + col] = val;
        }
    }
}

extern "C" void kernel_launch(void* const* d_in, const int* in_sizes, int n_in,
                              void* d_out, int out_size, void* d_ws, size_t ws_size,
                              hipStream_t stream)
{
    const float* x   = (const float*)d_in[0];
    const int*   ei[3] = { (const int*)d_in[1], (const int*)d_in[2], (const int*)d_in[3] };
    const float* Wp  = (const float*)d_in[6];
    const float* bp  = (const float*)d_in[7];
    const float* Wl  = (const float*)d_in[8];
    const float* bl  = (const float*)d_in[9];
    const float* Wr  = (const float*)d_in[10];
    const float* Wl2 = (const float*)d_in[11];
    const float* bl2 = (const float*)d_in[12];
    const float* Wr2 = (const float*)d_in[13];
    const float* g0  = (const float*)d_in[14];
    const float* b0  = (const float*)d_in[15];
    const float* g1  = (const float*)d_in[16];
    const float* b1  = (const float*)d_in[17];

    // ---- workspace layout (4-byte units) ----
    float* ws = (float*)d_ws;
    float*          agg  = ws;                                  // C1*64 = 9.6M
    float*          h    = ws + (size_t)C1n * 64;               // C1*128 = 19.2M
    unsigned short* xp   = (unsigned short*)(h + (size_t)C1n * 128); // C2*64 bf16 = 9.6M units
    int*            csr1 = (int*)((float*)xp + (size_t)C2n * 32);    // after xp
    int*            arr1 = csr1;                                // 3*C1 (deg -> rp in place)
    int*            fill1 = arr1 + 3 * (size_t)C1n;             // 3*C1
    int*            bsum1 = fill1 + 3 * (size_t)C1n;            // 1024
    int*            el1  = bsum1 + 1024;                        // 3*NE = 2.7M

    // layer-2 region overlays agg (free after out1 t=2) and xp (free after gath1 t=2)
    float* agg2 = agg;                                          // C0*128 = 6.4M
    int*   arr2 = (int*)(agg2 + (size_t)C0n * 128);             // 3*C0
    int*   fill2 = arr2 + 3 * (size_t)C0n;
    int*   bsum2 = fill2 + 3 * (size_t)C0n;                     // 1024
    int*   el2  = bsum2 + 1024;                                 // 3*E0
    float* h2   = (float*)xp;                                   // C0*128 = 6.4M

    const int nb1 = (C1n + 2047) / 2048;  // 74
    const int nb2 = (C0n + 2047) / 2048;  // 25

    // ---- CSR layer 1 (dst over full edge list, nV=C1) ----
    hipMemsetAsync(arr1, 0, 2 * 3 * (size_t)C1n * 4, stream);   // arr1 + fill1
    k_hist<<<dim3((NEn + 255) / 256, 3), 256, 0, stream>>>(
        ei[0] + NEn, ei[1] + NEn, ei[2] + NEn, arr1, NEn, C1n);
    k_scan_a<<<dim3(nb1, 3), 256, 0, stream>>>(arr1, C1n, bsum1, nb1);
    k_scan_b<<<dim3(1, 3), 256, 0, stream>>>(bsum1, nb1);
    k_scan_c<<<dim3(nb1, 3), 256, 0, stream>>>(arr1, C1n, bsum1, nb1);
    k_fill<<<dim3((NEn + 255) / 256, 3), 256, 0, stream>>>(
        ei[0], ei[1], ei[2], ei[0] + NEn, ei[1] + NEn, ei[2] + NEn,
        arr1, fill1, el1, NEn, C1n);

    // ---- layer 1 ----
    for (int t = 0; t < 3; t++) {
        k_proj<<<(C2n + 63) / 64, 256, 0, stream>>>(x, Wp + (size_t)t * 64 * 64,
                                                    bp + (size_t)t * 64, xp);
        k_gath1<<<(C1n + 3) / 4, 256, 0, stream>>>(arr1 + (size_t)t * C1n,
                                                   el1 + (size_t)t * NEn, xp, agg);
        k_out1<<<(C1n + 31) / 32, 256, 0, stream>>>(agg, x,
                                                    Wl + (size_t)t * 64 * 128,
                                                    Wr + (size_t)t * 64 * 128,
                                                    bl + (size_t)t * 128, h, t == 0);
    }
    k_ln<<<(C1n + 3) / 4, 256, 0, stream>>>(h, h, C1n, g0, b0);

    // ---- CSR layer 2 (first E0 edges, nV=C0) ----
    hipMemsetAsync(arr2, 0, 2 * 3 * (size_t)C0n * 4, stream);   // arr2 + fill2
    k_hist<<<dim3((E0n + 255) / 256, 3), 256, 0, stream>>>(
        ei[0] + NEn, ei[1] + NEn, ei[2] + NEn, arr2, E0n, C0n);
    k_scan_a<<<dim3(nb2, 3), 256, 0, stream>>>(arr2, C0n, bsum2, nb2);
    k_scan_b<<<dim3(1, 3), 256, 0, stream>>>(bsum2, nb2);
    k_scan_c<<<dim3(nb2, 3), 256, 0, stream>>>(arr2, C0n, bsum2, nb2);
    k_fill<<<dim3((E0n + 255) / 256, 3), 256, 0, stream>>>(
        ei[0], ei[1], ei[2], ei[0] + NEn, ei[1] + NEn, ei[2] + NEn,
        arr2, fill2, el2, E0n, C0n);

    // ---- layer 2 ----
    for (int t = 0; t < 3; t++) {
        k_gath2<<<(C0n + 3) / 4, 256, 0, stream>>>(arr2 + (size_t)t * C0n,
                                                   el2 + (size_t)t * E0n, h, agg2);
        k_out2<<<(C0n + 31) / 32, 256, 0, stream>>>(agg2, h,
                                                    Wl2 + (size_t)t * 128 * 128,
                                                    Wr2 + (size_t)t * 128 * 128,
                                                    bl2 + (size_t)t * 128, h2, t == 0);
    }
    k_ln<<<(C0n + 3) / 4, 256, 0, stream>>>(h2, (float*)d_out, C0n, g1, b1);
}

// Round 6
// 1124.120 us; speedup vs baseline: 5.6284x; 1.3418x over previous
//
#include <hip/hip_runtime.h>

#define C0n 50000
#define C1n 150000
#define C2n 300000
#define E0n 300000
#define E1n 600000
#define NEn (E0n + E1n)

typedef float  v4f    __attribute__((ext_vector_type(4)));
typedef float  v2f    __attribute__((ext_vector_type(2)));
typedef float  f32x4  __attribute__((ext_vector_type(4)));
typedef short  bf16x8 __attribute__((ext_vector_type(8)));
typedef unsigned short u16;

__device__ __forceinline__ u16 f2bf(float f){
    unsigned u = __builtin_bit_cast(unsigned, f);
    u += 0x7FFFu + ((u >> 16) & 1u);          // RNE
    return (u16)(u >> 16);
}
__device__ __forceinline__ float bf2f(u16 h){
    unsigned u = ((unsigned)h) << 16;
    return __builtin_bit_cast(float, u);
}
__device__ __forceinline__ f32x4 mfma16(bf16x8 a, bf16x8 b, f32x4 c){
    return __builtin_amdgcn_mfma_f32_16x16x32_bf16(a, b, c, 0, 0, 0);
}
__device__ __forceinline__ float red16(float v){
    v += __shfl_xor(v, 1); v += __shfl_xor(v, 2);
    v += __shfl_xor(v, 4); v += __shfl_xor(v, 8);
    return v;
}
// 8 consecutive f32 -> bf16x8 fragment (16B-aligned source)
__device__ __forceinline__ bf16x8 frag8(const float* __restrict__ p){
    v4f a = *(const v4f*)p, b = *(const v4f*)(p + 4);
    bf16x8 r;
    r[0] = (short)f2bf(a[0]); r[1] = (short)f2bf(a[1]);
    r[2] = (short)f2bf(a[2]); r[3] = (short)f2bf(a[3]);
    r[4] = (short)f2bf(b[0]); r[5] = (short)f2bf(b[1]);
    r[6] = (short)f2bf(b[2]); r[7] = (short)f2bf(b[3]);
    return r;
}

// ---------------- xp = relu(x @ Wp[t] + bp[t]) -> bf16, MFMA ----------------
// ntiles = C2n/16; tiles strictly ownership-partitioned: writes guarded by valid.
__global__ __launch_bounds__(256) void k_projm(const float* __restrict__ x,
    const float* __restrict__ Wp, const float* __restrict__ bp,
    u16* __restrict__ xp)
{
    __shared__ u16 Wt[64 * 72];      // [c][k], pad to 72
    __shared__ float bps[64];
    const int tid = threadIdx.x;
    if (tid < 64) bps[tid] = bp[tid];
    for (int idx = tid; idx < 64 * 64; idx += 256) {
        int k = idx >> 6, c = idx & 63;          // idx = k*64 + c
        Wt[c * 72 + k] = f2bf(Wp[idx]);
    }
    __syncthreads();

    const int lane = tid & 63, wid = tid >> 6;
    const int lr = lane & 15, lg = lane >> 4;
    const int ntiles = C2n / 16;                  // 18750
    int rt = blockIdx.x * 4 + wid;
    const bool valid = (rt < ntiles);
    if (rt > ntiles - 1) rt = ntiles - 1;         // clamp for loads only
    const int r0 = rt * 16;

    f32x4 acc[4];
#pragma unroll
    for (int n = 0; n < 4; n++) acc[n] = 0;

#pragma unroll
    for (int ks = 0; ks < 2; ks++) {
        bf16x8 a = frag8(&x[(size_t)(r0 + lr) * 64 + ks * 32 + 8 * lg]);
#pragma unroll
        for (int n = 0; n < 4; n++) {
            bf16x8 b = *(const bf16x8*)&Wt[(16 * n + lr) * 72 + ks * 32 + 8 * lg];
            acc[n] = mfma16(a, b, acc[n]);
        }
    }
    if (valid) {
#pragma unroll
        for (int n = 0; n < 4; n++) {
            const float bb = bps[16 * n + lr];
#pragma unroll
            for (int j = 0; j < 4; j++)
                xp[(size_t)(r0 + 4 * lg + j) * 64 + 16 * n + lr] =
                    f2bf(fmaxf(acc[n][j] + bb, 0.f));
        }
    }
}

// ---------------- CSR build: histogram ----------------
__global__ __launch_bounds__(256) void k_hist(const int* __restrict__ d0,
    const int* __restrict__ d1, const int* __restrict__ d2,
    int* __restrict__ deg, int nE, int nV)
{
    const int e = blockIdx.x * 256 + threadIdx.x;
    if (e >= nE) return;
    const int y = blockIdx.y;
    const int* d = (y == 0) ? d0 : (y == 1) ? d1 : d2;
    atomicAdd(&deg[(size_t)y * nV + d[e]], 1);
}

// ---------------- CSR build: exclusive scan ----------------
__global__ __launch_bounds__(256) void k_scan_a(int* __restrict__ a, int n,
    int* __restrict__ bsum, int nblk)
{
    __shared__ int sd[256];
    const int t = threadIdx.x, y = blockIdx.y;
    int* arr = a + (size_t)y * n;
    const int base = blockIdx.x * 2048 + t * 8;
    int v[8];
#pragma unroll
    for (int j = 0; j < 8; j++) v[j] = (base + j < n) ? arr[base + j] : 0;
    int tot = 0;
#pragma unroll
    for (int j = 0; j < 8; j++) { int tmp = v[j]; v[j] = tot; tot += tmp; }
    sd[t] = tot; __syncthreads();
    for (int off = 1; off < 256; off <<= 1) {
        int xv = (t >= off) ? sd[t - off] : 0;
        __syncthreads();
        sd[t] += xv;
        __syncthreads();
    }
    const int excl = sd[t] - tot;
#pragma unroll
    for (int j = 0; j < 8; j++)
        if (base + j < n) arr[base + j] = excl + v[j];
    if (t == 255) bsum[y * nblk + blockIdx.x] = sd[255];
}

__global__ __launch_bounds__(256) void k_scan_b(int* __restrict__ bsum, int nblk)
{
    __shared__ int sd[256];
    const int t = threadIdx.x, y = blockIdx.y;
    int val = (t < nblk) ? bsum[y * nblk + t] : 0;
    sd[t] = val; __syncthreads();
    for (int off = 1; off < 256; off <<= 1) {
        int xv = (t >= off) ? sd[t - off] : 0;
        __syncthreads();
        sd[t] += xv;
        __syncthreads();
    }
    if (t < nblk) bsum[y * nblk + t] = sd[t] - val;
}

__global__ __launch_bounds__(256) void k_scan_c(int* __restrict__ a, int n,
    const int* __restrict__ bsum, int nblk)
{
    const int t = threadIdx.x, y = blockIdx.y;
    int* arr = a + (size_t)y * n;
    const int base = blockIdx.x * 2048 + t * 8;
    const int add = bsum[y * nblk + blockIdx.x];
#pragma unroll
    for (int j = 0; j < 8; j++)
        if (base + j < n) arr[base + j] += add;
}

// ---------------- CSR build: fill ----------------
__global__ __launch_bounds__(256) void k_fill(const int* __restrict__ s0,
    const int* __restrict__ s1, const int* __restrict__ s2,
    const int* __restrict__ d0, const int* __restrict__ d1, const int* __restrict__ d2,
    const int* __restrict__ rp, int* __restrict__ fill, int* __restrict__ el,
    int nE, int nV)
{
    const int e = blockIdx.x * 256 + threadIdx.x;
    if (e >= nE) return;
    const int y = blockIdx.y;
    const int* s = (y == 0) ? s0 : (y == 1) ? s1 : s2;
    const int* d = (y == 0) ? d0 : (y == 1) ? d1 : d2;
    const int dd = d[e];
    const int pos = rp[(size_t)y * nV + dd] + atomicAdd(&fill[(size_t)y * nV + dd], 1);
    el[(size_t)y * nE + pos] = s[e];
}

// ---------------- gather layer1: agg[r] = mean of xp[src] (bf16 -> f32) ----------------
__global__ __launch_bounds__(256) void k_gath1(const int* __restrict__ rp,
    const int* __restrict__ el, const u16* __restrict__ xp,
    float* __restrict__ agg)
{
    const int gid = blockIdx.x * 4 + (threadIdx.x >> 6);
    if (gid >= C1n) return;
    const int lane = threadIdx.x & 63;
    const int b = rp[gid];
    const int e = (gid == C1n - 1) ? NEn : rp[gid + 1];
    float s = 0.f;
    for (int i = b; i < e; i++) {
        const int sr = el[i];
        s += bf2f(xp[(size_t)sr * 64 + lane]);
    }
    const float inv = 1.f / (float)max(e - b, 1);
    agg[(size_t)gid * 64 + lane] = s * inv;
}

// ------- per t: o = agg@Wl + bl + x@Wr ; o /= max(||o||,eps) ; h (=| +=) o -------
__global__ __launch_bounds__(256) void k_out1m(const float* __restrict__ agg,
    const float* __restrict__ x,
    const float* __restrict__ Wl, const float* __restrict__ Wr,
    const float* __restrict__ bl, float* __restrict__ h, int first)
{
    __shared__ u16 Wt[128 * 136];   // [c][k], pad to 136
    __shared__ float bls[128];
    const int tid = threadIdx.x;
    if (tid < 128) bls[tid] = bl[tid];
    for (int idx = tid; idx < 128 * 128; idx += 256) {
        int k = idx >> 7, c = idx & 127;
        float w = (k < 64) ? Wl[k * 128 + c] : Wr[(k - 64) * 128 + c];
        Wt[c * 136 + k] = f2bf(w);
    }
    __syncthreads();

    const int lane = tid & 63, wid = tid >> 6;
    const int lr = lane & 15, lg = lane >> 4;
    const int ntiles = C1n / 16;                  // 9375
    int rt = blockIdx.x * 4 + wid;
    const bool valid = (rt < ntiles);
    if (rt > ntiles - 1) rt = ntiles - 1;         // clamp for loads only
    const int r0 = rt * 16;

    f32x4 acc[8];
#pragma unroll
    for (int n = 0; n < 8; n++) acc[n] = 0;

#pragma unroll
    for (int ks = 0; ks < 4; ks++) {
        const float* Ap = (ks < 2) ? &agg[(size_t)(r0 + lr) * 64 + (ks & 1) * 32 + 8 * lg]
                                   : &x[(size_t)(r0 + lr) * 64 + (ks & 1) * 32 + 8 * lg];
        bf16x8 a = frag8(Ap);
#pragma unroll
        for (int n = 0; n < 8; n++) {
            bf16x8 b = *(const bf16x8*)&Wt[(16 * n + lr) * 136 + ks * 32 + 8 * lg];
            acc[n] = mfma16(a, b, acc[n]);
        }
    }

    // + bias, then row L2 norm (row = 4*lg + j spread over 16 lanes x 8 n-tiles)
    float ss[4] = {0.f, 0.f, 0.f, 0.f};
#pragma unroll
    for (int n = 0; n < 8; n++) {
        const float bb = bls[16 * n + lr];
#pragma unroll
        for (int j = 0; j < 4; j++) {
            acc[n][j] += bb;
            ss[j] += acc[n][j] * acc[n][j];
        }
    }
#pragma unroll
    for (int j = 0; j < 4; j++)
        ss[j] = 1.f / fmaxf(sqrtf(red16(ss[j])), 1e-12f);

    if (valid) {
#pragma unroll
        for (int n = 0; n < 8; n++) {
#pragma unroll
            for (int j = 0; j < 4; j++) {
                float val = acc[n][j] * ss[j];
                size_t o = (size_t)(r0 + 4 * lg + j) * 128 + 16 * n + lr;
                if (!first) val += h[o];
                h[o] = val;
            }
        }
    }
}

// ---------------- relu + layernorm; v = src/3 first ----------------
__global__ __launch_bounds__(256) void k_ln(const float* __restrict__ src,
    float* __restrict__ dst, int nrows,
    const float* __restrict__ g, const float* __restrict__ b)
{
    const int rowg = threadIdx.x >> 6, lane = threadIdx.x & 63;
    const long row = (long)blockIdx.x * 4 + rowg;
    if (row >= nrows) return;
    v2f v = *(const v2f*)&src[row * 128 + lane * 2];
    v *= (1.0f / 3.0f);
    v[0] = fmaxf(v[0], 0.f); v[1] = fmaxf(v[1], 0.f);
    float s = v[0] + v[1];
#pragma unroll
    for (int m = 32; m; m >>= 1) s += __shfl_xor(s, m);
    const float mu = s * (1.0f / 128.0f);
    const float d0 = v[0] - mu, d1 = v[1] - mu;
    float vs = d0 * d0 + d1 * d1;
#pragma unroll
    for (int m = 32; m; m >>= 1) vs += __shfl_xor(vs, m);
    const float rs = rsqrtf(vs * (1.0f / 128.0f) + 1e-5f);
    v2f gv = *(const v2f*)&g[lane * 2];
    v2f bv = *(const v2f*)&b[lane * 2];
    v2f o;
    o[0] = d0 * rs * gv[0] + bv[0];
    o[1] = d1 * rs * gv[1] + bv[1];
    *(v2f*)&dst[row * 128 + lane * 2] = o;
}

// ---------------- gather layer2: agg2[r] = mean of h1[src] (128 f32) ----------------
__global__ __launch_bounds__(256) void k_gath2(const int* __restrict__ rp,
    const int* __restrict__ el, const float* __restrict__ h1,
    float* __restrict__ agg2)
{
    const int gid = blockIdx.x * 4 + (threadIdx.x >> 6);
    if (gid >= C0n) return;
    const int lane = threadIdx.x & 63;
    const int b = rp[gid];
    const int e = (gid == C0n - 1) ? E0n : rp[gid + 1];
    v2f s; s[0] = 0.f; s[1] = 0.f;
    for (int i = b; i < e; i++) {
        const int sr = el[i];
        s += *(const v2f*)&h1[(size_t)sr * 128 + lane * 2];
    }
    const float inv = 1.f / (float)max(e - b, 1);
    *(v2f*)&agg2[(size_t)gid * 128 + lane * 2] = s * inv;
}

// ------- per t: h2 (=| +=) agg2@Wl2 + bl2 + h1@Wr2 -------
__global__ __launch_bounds__(256) void k_out2m(const float* __restrict__ agg2,
    const float* __restrict__ h1,
    const float* __restrict__ Wl2, const float* __restrict__ Wr2,
    const float* __restrict__ bl2, float* __restrict__ h2, int first)
{
    __shared__ u16 Wt[128 * 136];
    __shared__ float bs2[128];
    const int tid = threadIdx.x;
    if (tid < 128) bs2[tid] = bl2[tid];

    const int lane = tid & 63, wid = tid >> 6;
    const int lr = lane & 15, lg = lane >> 4;
    const int ntiles = C0n / 16;                  // 3125
    int rt = blockIdx.x * 4 + wid;
    const bool valid = (rt < ntiles);
    if (rt > ntiles - 1) rt = ntiles - 1;         // clamp for loads only
    const int r0 = rt * 16;

    f32x4 acc[8];
#pragma unroll
    for (int n = 0; n < 8; n++) acc[n] = 0;

    for (int hh = 0; hh < 2; hh++) {
        __syncthreads();
        const float* W = hh ? Wr2 : Wl2;
        for (int idx = tid; idx < 128 * 128; idx += 256) {
            int k = idx >> 7, c = idx & 127;
            Wt[c * 136 + k] = f2bf(W[idx]);       // idx = k*128 + c
        }
        __syncthreads();
        const float* A = hh ? h1 : agg2;
#pragma unroll
        for (int ks = 0; ks < 4; ks++) {
            bf16x8 a = frag8(&A[(size_t)(r0 + lr) * 128 + ks * 32 + 8 * lg]);
#pragma unroll
            for (int n = 0; n < 8; n++) {
                bf16x8 b = *(const bf16x8*)&Wt[(16 * n + lr) * 136 + ks * 32 + 8 * lg];
                acc[n] = mfma16(a, b, acc[n]);
            }
        }
    }

    if (valid) {
#pragma unroll
        for (int n = 0; n < 8; n++) {
            const float bb = bs2[16 * n + lr];
#pragma unroll
            for (int j = 0; j < 4; j++) {
                float val = acc[n][j] + bb;
                size_t o = (size_t)(r0 + 4 * lg + j) * 128 + 16 * n + lr;
                if (!first) val += h2[o];
                h2[o] = val;
            }
        }
    }
}

extern "C" void kernel_launch(void* const* d_in, const int* in_sizes, int n_in,
                              void* d_out, int out_size, void* d_ws, size_t ws_size,
                              hipStream_t stream)
{
    const float* x   = (const float*)d_in[0];
    const int*   ei[3] = { (const int*)d_in[1], (const int*)d_in[2], (const int*)d_in[3] };
    const float* Wp  = (const float*)d_in[6];
    const float* bp  = (const float*)d_in[7];
    const float* Wl  = (const float*)d_in[8];
    const float* bl  = (const float*)d_in[9];
    const float* Wr  = (const float*)d_in[10];
    const float* Wl2 = (const float*)d_in[11];
    const float* bl2 = (const float*)d_in[12];
    const float* Wr2 = (const float*)d_in[13];
    const float* g0  = (const float*)d_in[14];
    const float* b0  = (const float*)d_in[15];
    const float* g1  = (const float*)d_in[16];
    const float* b1  = (const float*)d_in[17];

    // ---- workspace layout (bytes) ----
    char* W = (char*)d_ws;
    float* agg  = (float*)(W + 0);           // C1*64  f32 = 38,400,000
    float* h    = (float*)(W + 38400000);    // C1*128 f32 = 76,800,000 -> ends 115,200,000
    u16*   xp   = (u16*)(W + 115200000);     // C2*64 bf16 = 38,400,000 -> ends 153,600,000
    int*   rp1  = (int*)(W + 153600000);     // 3*C1*4 = 1,800,000
    int*   fill1= (int*)(W + 155400000);     // 1,800,000
    int*   bsum = (int*)(W + 157200000);     // 4 KiB
    int*   el1  = (int*)(W + 157204096);     // 3*NE*4 = 10,800,000 -> ends 168,004,096
    // layer-2 overlays: agg region is dead after out1 t=2; xp dead after gath1 t=2
    float* agg2 = agg;                       // C0*128 f32 = 25,600,000
    int*   rp2  = (int*)(W + 25600000);      // 3*C0*4 = 600,000
    int*   fill2= (int*)(W + 26200000);      // 600,000
    int*   el2  = (int*)(W + 26800000);      // 3*E0*4 = 3,600,000 -> ends 30,400,000
    float* h2   = (float*)(W + 115200000);   // C0*128 f32 (overlays xp)

    const int nb1 = (C1n + 2047) / 2048;  // 74
    const int nb2 = (C0n + 2047) / 2048;  // 25

    // ---- CSR layer 1 (dst over full edge list, nV=C1) ----
    hipMemsetAsync(rp1, 0, 2 * 3 * (size_t)C1n * 4, stream);   // rp1 + fill1
    k_hist<<<dim3((NEn + 255) / 256, 3), 256, 0, stream>>>(
        ei[0] + NEn, ei[1] + NEn, ei[2] + NEn, rp1, NEn, C1n);
    k_scan_a<<<dim3(nb1, 3), 256, 0, stream>>>(rp1, C1n, bsum, nb1);
    k_scan_b<<<dim3(1, 3), 256, 0, stream>>>(bsum, nb1);
    k_scan_c<<<dim3(nb1, 3), 256, 0, stream>>>(rp1, C1n, bsum, nb1);
    k_fill<<<dim3((NEn + 255) / 256, 3), 256, 0, stream>>>(
        ei[0], ei[1], ei[2], ei[0] + NEn, ei[1] + NEn, ei[2] + NEn,
        rp1, fill1, el1, NEn, C1n);

    // ---- layer 1 ----
    for (int t = 0; t < 3; t++) {
        k_projm<<<(C2n / 16 + 3) / 4, 256, 0, stream>>>(x, Wp + (size_t)t * 64 * 64,
                                                        bp + (size_t)t * 64, xp);
        k_gath1<<<(C1n + 3) / 4, 256, 0, stream>>>(rp1 + (size_t)t * C1n,
                                                   el1 + (size_t)t * NEn, xp, agg);
        k_out1m<<<(C1n / 16 + 3) / 4, 256, 0, stream>>>(agg, x,
                                                        Wl + (size_t)t * 64 * 128,
                                                        Wr + (size_t)t * 64 * 128,
                                                        bl + (size_t)t * 128, h, t == 0);
    }
    k_ln<<<(C1n + 3) / 4, 256, 0, stream>>>(h, h, C1n, g0, b0);

    // ---- CSR layer 2 (first E0 edges, nV=C0) ----
    hipMemsetAsync(rp2, 0, 2 * 3 * (size_t)C0n * 4, stream);   // rp2 + fill2
    k_hist<<<dim3((E0n + 255) / 256, 3), 256, 0, stream>>>(
        ei[0] + NEn, ei[1] + NEn, ei[2] + NEn, rp2, E0n, C0n);
    k_scan_a<<<dim3(nb2, 3), 256, 0, stream>>>(rp2, C0n, bsum, nb2);
    k_scan_b<<<dim3(1, 3), 256, 0, stream>>>(bsum, nb2);
    k_scan_c<<<dim3(nb2, 3), 256, 0, stream>>>(rp2, C0n, bsum, nb2);
    k_fill<<<dim3((E0n + 255) / 256, 3), 256, 0, stream>>>(
        ei[0], ei[1], ei[2], ei[0] + NEn, ei[1] + NEn, ei[2] + NEn,
        rp2, fill2, el2, E0n, C0n);

    // ---- layer 2 ----
    for (int t = 0; t < 3; t++) {
        k_gath2<<<(C0n + 3) / 4, 256, 0, stream>>>(rp2 + (size_t)t * C0n,
                                                   el2 + (size_t)t * E0n, h, agg2);
        k_out2m<<<(C0n / 16 + 3) / 4, 256, 0, stream>>>(agg2, h,
                                                        Wl2 + (size_t)t * 128 * 128,
                                                        Wr2 + (size_t)t * 128 * 128,
                                                        bl2 + (size_t)t * 128, h2, t == 0);
    }
    k_ln<<<(C0n + 3) / 4, 256, 0, stream>>>(h2, (float*)d_out, C0n, g1, b1);
}

// Round 7
// 965.652 us; speedup vs baseline: 6.5521x; 1.1641x over previous
//
#include <hip/hip_runtime.h>

#define C0n 50000
#define C1n 150000
#define C2n 300000
#define E0n 300000
#define E1n 600000
#define NEn (E0n + E1n)

typedef float  v4f    __attribute__((ext_vector_type(4)));
typedef float  v2f    __attribute__((ext_vector_type(2)));
typedef float  f32x4  __attribute__((ext_vector_type(4)));
typedef short  bf16x8 __attribute__((ext_vector_type(8)));
typedef unsigned short u16;

__device__ __forceinline__ u16 f2bf(float f){
    unsigned u = __builtin_bit_cast(unsigned, f);
    u += 0x7FFFu + ((u >> 16) & 1u);          // RNE
    return (u16)(u >> 16);
}
__device__ __forceinline__ float bf2f(u16 h){
    unsigned u = ((unsigned)h) << 16;
    return __builtin_bit_cast(float, u);
}
__device__ __forceinline__ f32x4 mfma16(bf16x8 a, bf16x8 b, f32x4 c){
    return __builtin_amdgcn_mfma_f32_16x16x32_bf16(a, b, c, 0, 0, 0);
}
__device__ __forceinline__ float red16(float v){
    v += __shfl_xor(v, 1); v += __shfl_xor(v, 2);
    v += __shfl_xor(v, 4); v += __shfl_xor(v, 8);
    return v;
}
// 8 consecutive f32 -> bf16x8 fragment (16B-aligned source)
__device__ __forceinline__ bf16x8 frag8(const float* __restrict__ p){
    v4f a = *(const v4f*)p, b = *(const v4f*)(p + 4);
    bf16x8 r;
    r[0] = (short)f2bf(a[0]); r[1] = (short)f2bf(a[1]);
    r[2] = (short)f2bf(a[2]); r[3] = (short)f2bf(a[3]);
    r[4] = (short)f2bf(b[0]); r[5] = (short)f2bf(b[1]);
    r[6] = (short)f2bf(b[2]); r[7] = (short)f2bf(b[3]);
    return r;
}

// ---------------- xp = relu(x @ Wp[t] + bp[t]) -> bf16, MFMA ----------------
__global__ __launch_bounds__(256) void k_projm(const float* __restrict__ x,
    const float* __restrict__ Wp, const float* __restrict__ bp,
    u16* __restrict__ xp)
{
    __shared__ u16 Wt[64 * 72];      // [c][k], pad to 72
    __shared__ float bps[64];
    const int tid = threadIdx.x;
    if (tid < 64) bps[tid] = bp[tid];
    for (int idx = tid; idx < 64 * 64; idx += 256) {
        int k = idx >> 6, c = idx & 63;          // idx = k*64 + c
        Wt[c * 72 + k] = f2bf(Wp[idx]);
    }
    __syncthreads();

    const int lane = tid & 63, wid = tid >> 6;
    const int lr = lane & 15, lg = lane >> 4;
    const int ntiles = C2n / 16;                  // 18750
    int rt = blockIdx.x * 4 + wid;
    const bool valid = (rt < ntiles);
    if (rt > ntiles - 1) rt = ntiles - 1;         // clamp for loads only
    const int r0 = rt * 16;

    f32x4 acc[4];
#pragma unroll
    for (int n = 0; n < 4; n++) acc[n] = 0;

#pragma unroll
    for (int ks = 0; ks < 2; ks++) {
        bf16x8 a = frag8(&x[(size_t)(r0 + lr) * 64 + ks * 32 + 8 * lg]);
#pragma unroll
        for (int n = 0; n < 4; n++) {
            bf16x8 b = *(const bf16x8*)&Wt[(16 * n + lr) * 72 + ks * 32 + 8 * lg];
            acc[n] = mfma16(a, b, acc[n]);
        }
    }
    if (valid) {
#pragma unroll
        for (int n = 0; n < 4; n++) {
            const float bb = bps[16 * n + lr];
#pragma unroll
            for (int j = 0; j < 4; j++)
                xp[(size_t)(r0 + 4 * lg + j) * 64 + 16 * n + lr] =
                    f2bf(fmaxf(acc[n][j] + bb, 0.f));
        }
    }
}

// ---------------- CSR build: histogram ----------------
__global__ __launch_bounds__(256) void k_hist(const int* __restrict__ d0,
    const int* __restrict__ d1, const int* __restrict__ d2,
    int* __restrict__ deg, int nE, int nV)
{
    const int e = blockIdx.x * 256 + threadIdx.x;
    if (e >= nE) return;
    const int y = blockIdx.y;
    const int* d = (y == 0) ? d0 : (y == 1) ? d1 : d2;
    atomicAdd(&deg[(size_t)y * nV + d[e]], 1);
}

// ---------------- CSR build: exclusive scan ----------------
__global__ __launch_bounds__(256) void k_scan_a(int* __restrict__ a, int n,
    int* __restrict__ bsum, int nblk)
{
    __shared__ int sd[256];
    const int t = threadIdx.x, y = blockIdx.y;
    int* arr = a + (size_t)y * n;
    const int base = blockIdx.x * 2048 + t * 8;
    int v[8];
#pragma unroll
    for (int j = 0; j < 8; j++) v[j] = (base + j < n) ? arr[base + j] : 0;
    int tot = 0;
#pragma unroll
    for (int j = 0; j < 8; j++) { int tmp = v[j]; v[j] = tot; tot += tmp; }
    sd[t] = tot; __syncthreads();
    for (int off = 1; off < 256; off <<= 1) {
        int xv = (t >= off) ? sd[t - off] : 0;
        __syncthreads();
        sd[t] += xv;
        __syncthreads();
    }
    const int excl = sd[t] - tot;
#pragma unroll
    for (int j = 0; j < 8; j++)
        if (base + j < n) arr[base + j] = excl + v[j];
    if (t == 255) bsum[y * nblk + blockIdx.x] = sd[255];
}

__global__ __launch_bounds__(256) void k_scan_b(int* __restrict__ bsum, int nblk)
{
    __shared__ int sd[256];
    const int t = threadIdx.x, y = blockIdx.y;
    int val = (t < nblk) ? bsum[y * nblk + t] : 0;
    sd[t] = val; __syncthreads();
    for (int off = 1; off < 256; off <<= 1) {
        int xv = (t >= off) ? sd[t - off] : 0;
        __syncthreads();
        sd[t] += xv;
        __syncthreads();
    }
    if (t < nblk) bsum[y * nblk + t] = sd[t] - val;
}

__global__ __launch_bounds__(256) void k_scan_c(int* __restrict__ a, int n,
    const int* __restrict__ bsum, int nblk)
{
    const int t = threadIdx.x, y = blockIdx.y;
    int* arr = a + (size_t)y * n;
    const int base = blockIdx.x * 2048 + t * 8;
    const int add = bsum[y * nblk + blockIdx.x];
#pragma unroll
    for (int j = 0; j < 8; j++)
        if (base + j < n) arr[base + j] += add;
}

// ---------------- CSR build: fill ----------------
__global__ __launch_bounds__(256) void k_fill(const int* __restrict__ s0,
    const int* __restrict__ s1, const int* __restrict__ s2,
    const int* __restrict__ d0, const int* __restrict__ d1, const int* __restrict__ d2,
    const int* __restrict__ rp, int* __restrict__ fill, int* __restrict__ el,
    int nE, int nV)
{
    const int e = blockIdx.x * 256 + threadIdx.x;
    if (e >= nE) return;
    const int y = blockIdx.y;
    const int* s = (y == 0) ? s0 : (y == 1) ? s1 : s2;
    const int* d = (y == 0) ? d0 : (y == 1) ? d1 : d2;
    const int dd = d[e];
    const int pos = rp[(size_t)y * nV + dd] + atomicAdd(&fill[(size_t)y * nV + dd], 1);
    el[(size_t)y * nE + pos] = s[e];
}

// ---------------- gather layer1: agg_t[r] = mean of xp[src] (bf16 -> bf16) ----------------
__global__ __launch_bounds__(256) void k_gath1(const int* __restrict__ rp,
    const int* __restrict__ el, const u16* __restrict__ xp,
    u16* __restrict__ aggt)
{
    const int gid = blockIdx.x * 4 + (threadIdx.x >> 6);
    if (gid >= C1n) return;
    const int lane = threadIdx.x & 63;
    const int b = rp[gid];
    const int e = (gid == C1n - 1) ? NEn : rp[gid + 1];
    float s = 0.f;
    for (int i = b; i < e; i++) {
        const int sr = el[i];
        s += bf2f(xp[(size_t)sr * 64 + lane]);
    }
    const float inv = 1.f / (float)max(e - b, 1);
    aggt[(size_t)gid * 64 + lane] = f2bf(s * inv);
}

// ------- fused layer1: per t { o=[agg_t|x]@[Wl;Wr]+bl; o/=||o|| ; accumulate } ;
//         h1 = LN(relu(sum/3))  written ONCE (f32). Pure writes, guarded. -------
__global__ __launch_bounds__(256) void k_out1f(const u16* __restrict__ agg3,
    const float* __restrict__ x,
    const float* __restrict__ Wl, const float* __restrict__ Wr,
    const float* __restrict__ bl,
    const float* __restrict__ g0, const float* __restrict__ b0,
    float* __restrict__ h1)
{
    __shared__ u16 Wt[128 * 136];   // [c][k], pad to 136
    __shared__ float bls[3 * 128], gs[128], bs[128];
    const int tid = threadIdx.x;
    if (tid < 128) { gs[tid] = g0[tid]; bs[tid] = b0[tid]; }
    for (int i = tid; i < 384; i += 256) bls[i] = bl[i];

    const int lane = tid & 63, wid = tid >> 6;
    const int lr = lane & 15, lg = lane >> 4;
    const int ntiles = C1n / 16;                  // 9375
    int rt = blockIdx.x * 4 + wid;
    const bool valid = (rt < ntiles);
    if (rt > ntiles - 1) rt = ntiles - 1;         // clamp for loads only
    const int r0 = rt * 16;

    f32x4 hacc[8];
#pragma unroll
    for (int n = 0; n < 8; n++) hacc[n] = 0;

    for (int t = 0; t < 3; t++) {
        __syncthreads();                          // Wt reuse protection
        const float* WlT = Wl + (size_t)t * 64 * 128;
        const float* WrT = Wr + (size_t)t * 64 * 128;
        for (int idx = tid; idx < 128 * 128; idx += 256) {
            int k = idx >> 7, c = idx & 127;
            float w = (k < 64) ? WlT[k * 128 + c] : WrT[(k - 64) * 128 + c];
            Wt[c * 136 + k] = f2bf(w);
        }
        __syncthreads();

        const u16* aggT = agg3 + (size_t)t * C1n * 64;
        f32x4 ta[8];
#pragma unroll
        for (int n = 0; n < 8; n++) ta[n] = 0;
#pragma unroll
        for (int ks = 0; ks < 4; ks++) {
            bf16x8 a;
            if (ks < 2)
                a = *(const bf16x8*)&aggT[(size_t)(r0 + lr) * 64 + ks * 32 + 8 * lg];
            else
                a = frag8(&x[(size_t)(r0 + lr) * 64 + (ks - 2) * 32 + 8 * lg]);
#pragma unroll
            for (int n = 0; n < 8; n++) {
                bf16x8 b = *(const bf16x8*)&Wt[(16 * n + lr) * 136 + ks * 32 + 8 * lg];
                ta[n] = mfma16(a, b, ta[n]);
            }
        }
        // + bias, row L2 norm (row = 4*lg + j; cols spread over 16 lanes x 8 n-tiles)
        float ss[4] = {0.f, 0.f, 0.f, 0.f};
#pragma unroll
        for (int n = 0; n < 8; n++) {
            const float bb = bls[t * 128 + 16 * n + lr];
#pragma unroll
            for (int j = 0; j < 4; j++) {
                ta[n][j] += bb;
                ss[j] += ta[n][j] * ta[n][j];
            }
        }
#pragma unroll
        for (int j = 0; j < 4; j++)
            ss[j] = 1.f / fmaxf(sqrtf(red16(ss[j])), 1e-12f);
#pragma unroll
        for (int n = 0; n < 8; n++)
#pragma unroll
            for (int j = 0; j < 4; j++) hacc[n][j] += ta[n][j] * ss[j];
    }

    // relu + /3 + LayerNorm over 128 cols
    float mu[4] = {0.f, 0.f, 0.f, 0.f};
#pragma unroll
    for (int n = 0; n < 8; n++)
#pragma unroll
        for (int j = 0; j < 4; j++) {
            float v = fmaxf(hacc[n][j], 0.f) * (1.f / 3.f);
            hacc[n][j] = v; mu[j] += v;
        }
#pragma unroll
    for (int j = 0; j < 4; j++) mu[j] = red16(mu[j]) * (1.f / 128.f);
    float var[4] = {0.f, 0.f, 0.f, 0.f};
#pragma unroll
    for (int n = 0; n < 8; n++)
#pragma unroll
        for (int j = 0; j < 4; j++) {
            float d = hacc[n][j] - mu[j]; var[j] += d * d;
        }
#pragma unroll
    for (int j = 0; j < 4; j++) var[j] = rsqrtf(red16(var[j]) * (1.f / 128.f) + 1e-5f);

    if (valid) {
#pragma unroll
        for (int n = 0; n < 8; n++) {
            const float g = gs[16 * n + lr], bb = bs[16 * n + lr];
#pragma unroll
            for (int j = 0; j < 4; j++) {
                float o = (hacc[n][j] - mu[j]) * var[j] * g + bb;
                h1[(size_t)(r0 + 4 * lg + j) * 128 + 16 * n + lr] = o;
            }
        }
    }
}

// ---------------- gather layer2: agg2_t[r] = mean of h1[src] (f32 -> bf16) ----------------
__global__ __launch_bounds__(256) void k_gath2(const int* __restrict__ rp,
    const int* __restrict__ el, const float* __restrict__ h1,
    u16* __restrict__ agg2t)
{
    const int gid = blockIdx.x * 4 + (threadIdx.x >> 6);
    if (gid >= C0n) return;
    const int lane = threadIdx.x & 63;
    const int b = rp[gid];
    const int e = (gid == C0n - 1) ? E0n : rp[gid + 1];
    v2f s; s[0] = 0.f; s[1] = 0.f;
    for (int i = b; i < e; i++) {
        const int sr = el[i];
        s += *(const v2f*)&h1[(size_t)sr * 128 + lane * 2];
    }
    const float inv = 1.f / (float)max(e - b, 1);
    unsigned o = (unsigned)f2bf(s[0] * inv) | ((unsigned)f2bf(s[1] * inv) << 16);
    *(unsigned*)&agg2t[(size_t)gid * 128 + lane * 2] = o;
}

// ------- fused layer2: acc = sum_t [agg2_t|h1]@[Wl2;Wr2] ; out = LN(relu((acc+Σbl2)/3)) -------
__global__ __launch_bounds__(256) void k_out2f(const u16* __restrict__ agg2,
    const float* __restrict__ h1,
    const float* __restrict__ Wl2, const float* __restrict__ Wr2,
    const float* __restrict__ bl2,
    const float* __restrict__ g1, const float* __restrict__ b1,
    float* __restrict__ out)
{
    __shared__ u16 Wt[128 * 136];
    __shared__ float bsm[128], gs[128], bs[128];
    const int tid = threadIdx.x;
    if (tid < 128) {
        gs[tid] = g1[tid]; bs[tid] = b1[tid];
        bsm[tid] = bl2[tid] + bl2[128 + tid] + bl2[256 + tid];
    }
    const int lane = tid & 63, wid = tid >> 6;
    const int lr = lane & 15, lg = lane >> 4;
    const int ntiles = C0n / 16;                  // 3125
    int rt = blockIdx.x * 4 + wid;
    const bool valid = (rt < ntiles);
    if (rt > ntiles - 1) rt = ntiles - 1;         // clamp for loads only
    const int r0 = rt * 16;

    f32x4 acc[8];
#pragma unroll
    for (int n = 0; n < 8; n++) acc[n] = 0;

    for (int t = 0; t < 3; t++) {
        for (int hh = 0; hh < 2; hh++) {
            __syncthreads();                      // Wt reuse protection
            const float* W = hh ? Wr2 + (size_t)t * 128 * 128
                                : Wl2 + (size_t)t * 128 * 128;
            for (int idx = tid; idx < 128 * 128; idx += 256) {
                int k = idx >> 7, c = idx & 127;
                Wt[c * 136 + k] = f2bf(W[idx]);   // idx = k*128 + c
            }
            __syncthreads();
#pragma unroll
            for (int ks = 0; ks < 4; ks++) {
                bf16x8 a;
                if (hh == 0)
                    a = *(const bf16x8*)&agg2[(size_t)t * C0n * 128 +
                                              (size_t)(r0 + lr) * 128 + ks * 32 + 8 * lg];
                else
                    a = frag8(&h1[(size_t)(r0 + lr) * 128 + ks * 32 + 8 * lg]);
#pragma unroll
                for (int n = 0; n < 8; n++) {
                    bf16x8 b = *(const bf16x8*)&Wt[(16 * n + lr) * 136 + ks * 32 + 8 * lg];
                    acc[n] = mfma16(a, b, acc[n]);
                }
            }
        }
    }

    // (acc + Σbias)/3, relu, LN
    float mu[4] = {0.f, 0.f, 0.f, 0.f};
#pragma unroll
    for (int n = 0; n < 8; n++) {
        const float bb = bsm[16 * n + lr];
#pragma unroll
        for (int j = 0; j < 4; j++) {
            float v = fmaxf((acc[n][j] + bb) * (1.f / 3.f), 0.f);
            acc[n][j] = v; mu[j] += v;
        }
    }
#pragma unroll
    for (int j = 0; j < 4; j++) mu[j] = red16(mu[j]) * (1.f / 128.f);
    float var[4] = {0.f, 0.f, 0.f, 0.f};
#pragma unroll
    for (int n = 0; n < 8; n++)
#pragma unroll
        for (int j = 0; j < 4; j++) {
            float d = acc[n][j] - mu[j]; var[j] += d * d;
        }
#pragma unroll
    for (int j = 0; j < 4; j++) var[j] = rsqrtf(red16(var[j]) * (1.f / 128.f) + 1e-5f);

    if (valid) {
#pragma unroll
        for (int n = 0; n < 8; n++) {
            const float g = gs[16 * n + lr], bb = bs[16 * n + lr];
#pragma unroll
            for (int j = 0; j < 4; j++) {
                float o = (acc[n][j] - mu[j]) * var[j] * g + bb;
                out[(size_t)(r0 + 4 * lg + j) * 128 + 16 * n + lr] = o;
            }
        }
    }
}

extern "C" void kernel_launch(void* const* d_in, const int* in_sizes, int n_in,
                              void* d_out, int out_size, void* d_ws, size_t ws_size,
                              hipStream_t stream)
{
    const float* x   = (const float*)d_in[0];
    const int*   ei[3] = { (const int*)d_in[1], (const int*)d_in[2], (const int*)d_in[3] };
    const float* Wp  = (const float*)d_in[6];
    const float* bp  = (const float*)d_in[7];
    const float* Wl  = (const float*)d_in[8];
    const float* bl  = (const float*)d_in[9];
    const float* Wr  = (const float*)d_in[10];
    const float* Wl2 = (const float*)d_in[11];
    const float* bl2 = (const float*)d_in[12];
    const float* Wr2 = (const float*)d_in[13];
    const float* g0  = (const float*)d_in[14];
    const float* b0  = (const float*)d_in[15];
    const float* g1  = (const float*)d_in[16];
    const float* b1  = (const float*)d_in[17];

    // ---- workspace layout (bytes) ----
    char* W = (char*)d_ws;
    u16*   agg3 = (u16*)(W + 0);             // 3*C1*64 bf16 = 57,600,000
    u16*   xp   = (u16*)(W + 57600000);      // C2*64 bf16   = 38,400,000 -> 96,000,000
    float* h1   = (float*)(W + 96000000);    // C1*128 f32   = 76,800,000 -> 172,800,000
    int*   rp1  = (int*)(W + 172800000);     // 3*C1*4 = 1,800,000
    int*   fill1= (int*)(W + 174600000);     // 1,800,000
    int*   bsum = (int*)(W + 176400000);     // 4 KiB
    int*   el1  = (int*)(W + 176404096);     // 3*NE*4 = 10,800,000 -> ends 187,204,096
    // layer-2 overlays: agg3/xp dead after out1f
    u16*   agg2 = (u16*)(W + 0);             // 3*C0*128 bf16 = 38,400,000
    int*   rp2  = (int*)(W + 38400000);      // 600,000
    int*   fill2= (int*)(W + 39000000);      // 600,000
    int*   el2  = (int*)(W + 39600000);      // 3*E0*4 = 3,600,000 -> ends 43,200,000

    const int nb1 = (C1n + 2047) / 2048;  // 74
    const int nb2 = (C0n + 2047) / 2048;  // 25

    // ---- CSR layer 1 (dst over full edge list, nV=C1) ----
    hipMemsetAsync(rp1, 0, 2 * 3 * (size_t)C1n * 4, stream);   // rp1 + fill1
    k_hist<<<dim3((NEn + 255) / 256, 3), 256, 0, stream>>>(
        ei[0] + NEn, ei[1] + NEn, ei[2] + NEn, rp1, NEn, C1n);
    k_scan_a<<<dim3(nb1, 3), 256, 0, stream>>>(rp1, C1n, bsum, nb1);
    k_scan_b<<<dim3(1, 3), 256, 0, stream>>>(bsum, nb1);
    k_scan_c<<<dim3(nb1, 3), 256, 0, stream>>>(rp1, C1n, bsum, nb1);
    k_fill<<<dim3((NEn + 255) / 256, 3), 256, 0, stream>>>(
        ei[0], ei[1], ei[2], ei[0] + NEn, ei[1] + NEn, ei[2] + NEn,
        rp1, fill1, el1, NEn, C1n);

    // ---- layer 1: per t proj + gather (xp single-buffered), then fused out+LN ----
    for (int t = 0; t < 3; t++) {
        k_projm<<<(C2n / 16 + 3) / 4, 256, 0, stream>>>(x, Wp + (size_t)t * 64 * 64,
                                                        bp + (size_t)t * 64, xp);
        k_gath1<<<(C1n + 3) / 4, 256, 0, stream>>>(rp1 + (size_t)t * C1n,
                                                   el1 + (size_t)t * NEn, xp,
                                                   agg3 + (size_t)t * C1n * 64);
    }
    k_out1f<<<(C1n / 16 + 3) / 4, 256, 0, stream>>>(agg3, x, Wl, Wr, bl, g0, b0, h1);

    // ---- CSR layer 2 (first E0 edges, nV=C0) ----
    hipMemsetAsync(rp2, 0, 2 * 3 * (size_t)C0n * 4, stream);   // rp2 + fill2
    k_hist<<<dim3((E0n + 255) / 256, 3), 256, 0, stream>>>(
        ei[0] + NEn, ei[1] + NEn, ei[2] + NEn, rp2, E0n, C0n);
    k_scan_a<<<dim3(nb2, 3), 256, 0, stream>>>(rp2, C0n, bsum, nb2);
    k_scan_b<<<dim3(1, 3), 256, 0, stream>>>(bsum, nb2);
    k_scan_c<<<dim3(nb2, 3), 256, 0, stream>>>(rp2, C0n, bsum, nb2);
    k_fill<<<dim3((E0n + 255) / 256, 3), 256, 0, stream>>>(
        ei[0], ei[1], ei[2], ei[0] + NEn, ei[1] + NEn, ei[2] + NEn,
        rp2, fill2, el2, E0n, C0n);

    // ---- layer 2: gathers, then fused out+LN -> d_out ----
    for (int t = 0; t < 3; t++)
        k_gath2<<<(C0n + 3) / 4, 256, 0, stream>>>(rp2 + (size_t)t * C0n,
                                                   el2 + (size_t)t * E0n, h1,
                                                   agg2 + (size_t)t * C0n * 128);
    k_out2f<<<(C0n / 16 + 3) / 4, 256, 0, stream>>>(agg2, h1, Wl2, Wr2, bl2, g1, b1,
                                                    (float*)d_out);
}